// Round 3
// baseline (83.063 us; speedup 1.0000x reference)
//
#include <hip/hip_runtime.h>
#include <hip/hip_bf16.h>

#define BATCH 16384
#define NCLS  1000
#define NPAD  1024
#define FDIM  512

// cbt layout per cblk: 16 slabs * 16KB ([chunk4][class256]x16B) + tail 8KB
#define CBLK_STRIDE 270336
#define TAIL_OFF    262144

typedef __bf16 bf16x4 __attribute__((ext_vector_type(4)));
typedef __bf16 bf16x8 __attribute__((ext_vector_type(8)));
typedef float  f32x16 __attribute__((ext_vector_type(16)));

#define GLOBAL_AS __attribute__((address_space(1)))
#define LDS_AS    __attribute__((address_space(3)))

#define VMCNT(n) asm volatile("s_waitcnt vmcnt(" #n ")" ::: "memory")
#define LGKM0()  asm volatile("s_waitcnt lgkmcnt(0)" ::: "memory")
#define BAR()    do { LGKM0(); __builtin_amdgcn_s_barrier(); \
                      __builtin_amdgcn_sched_barrier(0); } while (0)

// ---------------------------------------------------------------------------
// prep: centers fp32 [1000][512] -> cbt, pre-tiled to the main kernel's LDS
// slab image. k<512: bf16(center); tail chunk0 holds (h=bf16(-cn/2),
// l=residual, 0...); pad classes: zeros, h=-1e30.
// One 64-thread wave per class; thread t owns k-chunk t (8 values).
// ---------------------------------------------------------------------------
__global__ __launch_bounds__(64) void prep_centers(
    const float* __restrict__ centers, char* __restrict__ cbt)
{
    const int c = blockIdx.x, t = threadIdx.x;       // c 0..1023, t 0..63
    const int cblk = c >> 8, cl = c & 255;
    char* base = cbt + (size_t)cblk * CBLK_STRIDE;

    float4 f0 = make_float4(0.f, 0.f, 0.f, 0.f);
    float4 f1 = make_float4(0.f, 0.f, 0.f, 0.f);
    if (c < NCLS) {
        f0 = *(const float4*)(centers + (size_t)c * FDIM + t * 8);
        f1 = *(const float4*)(centers + (size_t)c * FDIM + t * 8 + 4);
    }
    bf16x8 b;
    b[0] = (__bf16)f0.x; b[1] = (__bf16)f0.y; b[2] = (__bf16)f0.z; b[3] = (__bf16)f0.w;
    b[4] = (__bf16)f1.x; b[5] = (__bf16)f1.y; b[6] = (__bf16)f1.z; b[7] = (__bf16)f1.w;
    // chunk t -> slab t>>2, within-slab chunk t&3
    *(bf16x8*)(base + (t >> 2) * 16384 + (t & 3) * 4096 + cl * 16) = b;

    float ssum = f0.x*f0.x + f0.y*f0.y + f0.z*f0.z + f0.w*f0.w
               + f1.x*f1.x + f1.y*f1.y + f1.z*f1.z + f1.w*f1.w;
    #pragma unroll
    for (int o = 32; o > 0; o >>= 1) ssum += __shfl_down(ssum, o);
    if (t == 0) {
        const float hf = (c < NCLS) ? (-0.5f * ssum) : -1e30f;
        const __bf16 h = (__bf16)hf;
        const __bf16 l = (c < NCLS) ? (__bf16)(hf - (float)h) : (__bf16)0.f;
        bf16x8 tl;
        #pragma unroll
        for (int e = 0; e < 8; ++e) tl[e] = (__bf16)0.f;
        tl[0] = h; tl[1] = l;
        *(bf16x8*)(base + TAIL_OFF + cl * 16) = tl;          // tail chunk 0
        bf16x8 z;
        #pragma unroll
        for (int e = 0; e < 8; ++e) z[e] = (__bf16)0.f;
        *(bf16x8*)(base + TAIL_OFF + 4096 + cl * 16) = z;    // tail chunk 1
    }
}

// ---------------------------------------------------------------------------
// main: classes-as-M GEMM, acc[class][batch] = dot(c,x) - cn/2  (s = -2*acc)
//  block 256 cls x 256 batch, 8 waves (2M x 4N), wave 128x64 (4x2 frags 32x32)
//  grid mapping: bid = cblk*64 + bblk  -> all 4 cblks of a bblk on one XCD
//  BK=32, 16 slabs, triple-buffered, depth-2 prefetch, counted vmcnt(6)
//  A: cbt slab image -> pure contiguous memcpy via global_load_lds (2/wave)
//  B: x fp32 reg-staged (4 fully-coalesced dwordx4/wave), cvt, ds_write_b64
//  LDS: A 3x16K @0 | B 3x16K @48K | tailA 8K @96K | scratch @104K
// ---------------------------------------------------------------------------
__global__ __launch_bounds__(512, 2) void trip_main(
    const float* __restrict__ x, const int* __restrict__ labels,
    const char* __restrict__ cbt, float* __restrict__ mxp,
    float* __restrict__ dap)
{
    extern __shared__ char lds[];
    const int t    = threadIdx.x;
    const int lane = t & 63;
    const int w    = t >> 6;          // 0..7
    const int wN   = w & 3, wM = w >> 2;
    const int l31  = lane & 31, hi = lane >> 5;
    const int bid  = blockIdx.x;
    const int cblk = bid >> 6;        // 0..3
    const int bblk = bid & 63;        // 0..63 -> XCD = bblk & 7
    const int class0 = cblk * 256;
    const int row0   = bblk * 256;
    const char* cbB  = cbt + (size_t)cblk * CBLK_STRIDE;

    auto stageA = [&](int ko, int ai) {   // 16KB memcpy, 2 instr/thread
        const char* src = cbB + ko * 16384 + w * 1024 + lane * 16;
        char* dst = lds + ai * 16384 + w * 1024 + lane * 16;
        __builtin_amdgcn_global_load_lds((const GLOBAL_AS void*)src,
                                         (LDS_AS void*)dst, 16, 0, 0);
        __builtin_amdgcn_global_load_lds((const GLOBAL_AS void*)(src + 8192),
                                         (LDS_AS void*)(dst + 8192), 16, 0, 0);
    };
    auto loadB = [&](int ko, float4* br) { // 4 dwordx4/lane, 8 full lines/instr
        const float* src = x + (size_t)row0 * FDIM + ko * 32
                         + (size_t)(w * 32 + (lane >> 3)) * FDIM + (lane & 7) * 4;
        #pragma unroll
        for (int j = 0; j < 4; ++j)
            br[j] = *(const float4*)(src + (size_t)j * 8 * FDIM);
    };
    auto writeB = [&](const float4* br, int bi) { // 4 ds_write_b64
        char* dst = lds + 49152 + bi * 16384
                  + ((lane & 7) >> 1) * 4096 + (lane & 1) * 8;
        #pragma unroll
        for (int j = 0; j < 4; ++j) {
            bf16x4 v;
            v[0] = (__bf16)br[j].x; v[1] = (__bf16)br[j].y;
            v[2] = (__bf16)br[j].z; v[3] = (__bf16)br[j].w;
            *(bf16x4*)(dst + (w * 32 + j * 8 + (lane >> 3)) * 16) = v;
        }
    };

    f32x16 acc[4][2];
    #pragma unroll
    for (int mi = 0; mi < 4; ++mi)
        #pragma unroll
        for (int ni = 0; ni < 2; ++ni)
            #pragma unroll
            for (int r = 0; r < 16; ++r) acc[mi][ni][r] = 0.f;

    auto compute = [&](int buf) {
        const char* A = lds + buf * 16384;
        const char* B = lds + 49152 + buf * 16384;
        #pragma unroll
        for (int ks = 0; ks < 2; ++ks) {
            const int chunk = ks * 2 + hi;
            bf16x8 a[4], b[2];
            #pragma unroll
            for (int mi = 0; mi < 4; ++mi)
                a[mi] = *(const bf16x8*)(A + chunk * 4096 + (wM * 128 + mi * 32 + l31) * 16);
            #pragma unroll
            for (int ni = 0; ni < 2; ++ni)
                b[ni] = *(const bf16x8*)(B + chunk * 4096 + (wN * 64 + ni * 32 + l31) * 16);
            #pragma unroll
            for (int mi = 0; mi < 4; ++mi)
                #pragma unroll
                for (int ni = 0; ni < 2; ++ni)
                    acc[mi][ni] = __builtin_amdgcn_mfma_f32_32x32x16_bf16(
                        a[mi], b[ni], acc[mi][ni], 0, 0, 0);
        }
    };

    // ---- prologue (vmem ledger: lab 2, tail 1, A0 2, B0 4, A1 2, B1 4) ----
    const int lab0 = labels[row0 + wN * 64 + l31];
    const int lab1 = labels[row0 + wN * 64 + 32 + l31];
    {   // tail A: 8KB memcpy, 1 instr/thread
        const char* src = cbB + TAIL_OFF + t * 16;
        char* dst = lds + 98304 + t * 16;
        __builtin_amdgcn_global_load_lds((const GLOBAL_AS void*)src,
                                         (LDS_AS void*)dst, 16, 0, 0);
    }
    float4 br0[4], br1[4];
    stageA(0, 0); loadB(0, br0);
    stageA(1, 1); loadB(1, br1);
    VMCNT(6);            // drain lab+tail+slab0; keep slab1's 6 in flight
    writeB(br0, 0);
    BAR();

    // ---- K pipeline: 16 slabs of 32 ----
    int cur = 0;
    #pragma unroll 1
    for (int tt = 0; tt < 16; ++tt) {
        const int wr  = (cur + 1 >= 3) ? cur - 2 : cur + 1;   // (tt+1)%3
        const int pre = (cur + 2 >= 3) ? cur - 1 : cur + 2;   // (tt+2)%3
        if (tt < 14) {
            stageA(tt + 2, pre);
            loadB(tt + 2, (tt & 1) ? br1 : br0);
            VMCNT(6);    // drain slab tt+1 (A DMA + B regs); keep tt+2
        } else {
            VMCNT(0);
        }
        if (tt < 15) writeB((tt & 1) ? br0 : br1, wr);
        compute(cur);
        BAR();
        cur = wr;
    }

    // ---- tail k-step (k 512..527): A from tail LDS, B = (1,1,0,...) ----
    {
        const char* T = lds + 98304;
        bf16x8 bt;
        #pragma unroll
        for (int e = 0; e < 8; ++e) bt[e] = (__bf16)0.f;
        if (hi == 0) { bt[0] = (__bf16)1.0f; bt[1] = (__bf16)1.0f; }
        #pragma unroll
        for (int mi = 0; mi < 4; ++mi) {
            bf16x8 a = *(const bf16x8*)(T + hi * 4096 + (wM * 128 + mi * 32 + l31) * 16);
            #pragma unroll
            for (int ni = 0; ni < 2; ++ni)
                acc[mi][ni] = __builtin_amdgcn_mfma_f32_32x32x16_bf16(
                    a, bt, acc[mi][ni], 0, 0, 0);
        }
    }

    // ---- epilogue: per-lane max over non-label classes + label acc ----
    const int labBase = class0 + wM * 128 + hi * 4;
    const int labA0 = lab0 - labBase;
    const int labA1 = lab1 - labBase;
    float MX0 = -3e38f, MX1 = -3e38f, DA0 = -3e38f, DA1 = -3e38f;
    #pragma unroll
    for (int mi = 0; mi < 4; ++mi) {
        #pragma unroll
        for (int r = 0; r < 16; ++r) {
            const int pat = mi * 32 + (r & 3) + 8 * (r >> 2);
            {
                const float a = acc[mi][0][r];
                const bool is = (labA0 == pat);
                MX0 = fmaxf(MX0, is ? -3e38f : a);
                DA0 = is ? a : DA0;
            }
            {
                const float a = acc[mi][1][r];
                const bool is = (labA1 == pat);
                MX1 = fmaxf(MX1, is ? -3e38f : a);
                DA1 = is ? a : DA1;
            }
        }
    }
    MX0 = fmaxf(MX0, __shfl_xor(MX0, 32));
    DA0 = fmaxf(DA0, __shfl_xor(DA0, 32));
    MX1 = fmaxf(MX1, __shfl_xor(MX1, 32));
    DA1 = fmaxf(DA1, __shfl_xor(DA1, 32));

    // ---- merge the two M-waves via scratch, store partials ----
    float* sc = (float*)(lds + 104 * 1024);   // [256] MX, [256] DA
    const int i0 = (wN * 2 + 0) * 32 + l31;
    const int i1 = (wN * 2 + 1) * 32 + l31;
    if (wM == 1 && hi == 0) {
        sc[i0] = MX0; sc[256 + i0] = DA0;
        sc[i1] = MX1; sc[256 + i1] = DA1;
    }
    __syncthreads();
    if (wM == 0 && hi == 0) {
        const float M0 = fmaxf(MX0, sc[i0]),  D0 = fmaxf(DA0, sc[256 + i0]);
        const float M1 = fmaxf(MX1, sc[i1]),  D1 = fmaxf(DA1, sc[256 + i1]);
        const int rg = row0 + wN * 64 + l31;
        mxp[cblk * BATCH + rg]      = M0;
        dap[cblk * BATCH + rg]      = D0;
        mxp[cblk * BATCH + rg + 32] = M1;
        dap[cblk * BATCH + rg + 32] = D1;
    }
}

// ---------------------------------------------------------------------------
__global__ __launch_bounds__(256) void combine1(
    const float* __restrict__ mxp, const float* __restrict__ dap,
    const float* __restrict__ margin, float* __restrict__ partial)
{
    const int t = threadIdx.x;
    const int row = blockIdx.x * 256 + t;
    float mx = mxp[row];
    mx = fmaxf(mx, mxp[BATCH + row]);
    mx = fmaxf(mx, mxp[2 * BATCH + row]);
    mx = fmaxf(mx, mxp[3 * BATCH + row]);
    float da = dap[row];
    da = fmaxf(da, dap[BATCH + row]);
    da = fmaxf(da, dap[2 * BATCH + row]);
    da = fmaxf(da, dap[3 * BATCH + row]);
    // dist = -2*da, dist_min = -2*mx
    float loss = fmaxf(margin[0] - 2.f * da + 2.f * mx, 0.f);
    __shared__ float red[4];
    #pragma unroll
    for (int o = 32; o > 0; o >>= 1) loss += __shfl_down(loss, o);
    if ((t & 63) == 0) red[t >> 6] = loss;
    __syncthreads();
    if (t == 0) partial[blockIdx.x] = red[0] + red[1] + red[2] + red[3];
}

__global__ __launch_bounds__(64) void combine2(
    const float* __restrict__ partial, float* __restrict__ out)
{
    float s = partial[threadIdx.x];
    #pragma unroll
    for (int o = 32; o > 0; o >>= 1) s += __shfl_down(s, o);
    if (threadIdx.x == 0) out[0] = s * (1.0f / BATCH);
}

// ---------------------------------------------------------------------------
extern "C" void kernel_launch(void* const* d_in, const int* in_sizes, int n_in,
                              void* d_out, int out_size, void* d_ws, size_t ws_size,
                              hipStream_t stream)
{
    const float* x       = (const float*)d_in[0];
    const int*   labels  = (const int*)d_in[1];
    const float* centers = (const float*)d_in[2];
    const float* margin  = (const float*)d_in[3];
    float* out = (float*)d_out;

    char* ws = (char*)d_ws;
    char*  cbt  = ws;                                  // 1,081,344 B
    float* mxp  = (float*)(ws + 1081344);              //   262,144 B
    float* dap  = (float*)(ws + 1343488);              //   262,144 B
    float* part = (float*)(ws + 1605632);              //       256 B

    (void)hipFuncSetAttribute((const void*)trip_main,
                              hipFuncAttributeMaxDynamicSharedMemorySize, 110592);

    prep_centers<<<NPAD, 64, 0, stream>>>(centers, cbt);
    trip_main<<<256, 512, 110592, stream>>>(x, labels, cbt, mxp, dap);
    combine1<<<64, 256, 0, stream>>>(mxp, dap, margin, part);
    combine2<<<1, 64, 0, stream>>>(part, out);
}

// Round 4
// 33.505 us; speedup vs baseline: 2.4792x; 2.4792x over previous
//
#include <hip/hip_runtime.h>
#include <hip/hip_bf16.h>

#define BATCH 16384
#define NCLS  1000
#define NPAD  1024
#define FDIM  512

// cbt layout per cblk: 16 slabs * 16KB ([chunk4][class256]x16B) + tail 8KB
#define CBLK_STRIDE 270336
#define TAIL_OFF    262144

typedef __bf16 bf16x4 __attribute__((ext_vector_type(4)));
typedef __bf16 bf16x8 __attribute__((ext_vector_type(8)));
typedef float  f32x16 __attribute__((ext_vector_type(16)));

#define GLOBAL_AS __attribute__((address_space(1)))
#define LDS_AS    __attribute__((address_space(3)))

#define VMCNT(n) asm volatile("s_waitcnt vmcnt(" #n ")" ::: "memory")
#define LGKM0()  asm volatile("s_waitcnt lgkmcnt(0)" ::: "memory")
#define BAR()    do { LGKM0(); __builtin_amdgcn_s_barrier(); \
                      __builtin_amdgcn_sched_barrier(0); } while (0)

// ---------------------------------------------------------------------------
// prep: centers fp32 [1000][512] -> cbt, pre-tiled to the main kernel's LDS
// slab image. k<512: bf16(center); tail chunk0 holds (h=bf16(-cn/2),
// l=residual, 0...); pad classes: zeros, h=-1e30.
// ---------------------------------------------------------------------------
__global__ __launch_bounds__(64) void prep_centers(
    const float* __restrict__ centers, char* __restrict__ cbt)
{
    const int c = blockIdx.x, t = threadIdx.x;       // c 0..1023, t 0..63
    const int cblk = c >> 8, cl = c & 255;
    char* base = cbt + (size_t)cblk * CBLK_STRIDE;

    float4 f0 = make_float4(0.f, 0.f, 0.f, 0.f);
    float4 f1 = make_float4(0.f, 0.f, 0.f, 0.f);
    if (c < NCLS) {
        f0 = *(const float4*)(centers + (size_t)c * FDIM + t * 8);
        f1 = *(const float4*)(centers + (size_t)c * FDIM + t * 8 + 4);
    }
    bf16x8 b;
    b[0] = (__bf16)f0.x; b[1] = (__bf16)f0.y; b[2] = (__bf16)f0.z; b[3] = (__bf16)f0.w;
    b[4] = (__bf16)f1.x; b[5] = (__bf16)f1.y; b[6] = (__bf16)f1.z; b[7] = (__bf16)f1.w;
    *(bf16x8*)(base + (t >> 2) * 16384 + (t & 3) * 4096 + cl * 16) = b;

    float ssum = f0.x*f0.x + f0.y*f0.y + f0.z*f0.z + f0.w*f0.w
               + f1.x*f1.x + f1.y*f1.y + f1.z*f1.z + f1.w*f1.w;
    #pragma unroll
    for (int o = 32; o > 0; o >>= 1) ssum += __shfl_down(ssum, o);
    if (t == 0) {
        const float hf = (c < NCLS) ? (-0.5f * ssum) : -1e30f;
        const __bf16 h = (__bf16)hf;
        const __bf16 l = (c < NCLS) ? (__bf16)(hf - (float)h) : (__bf16)0.f;
        bf16x8 tl;
        #pragma unroll
        for (int e = 0; e < 8; ++e) tl[e] = (__bf16)0.f;
        tl[0] = h; tl[1] = l;
        *(bf16x8*)(base + TAIL_OFF + cl * 16) = tl;          // tail chunk 0
        bf16x8 z;
        #pragma unroll
        for (int e = 0; e < 8; ++e) z[e] = (__bf16)0.f;
        *(bf16x8*)(base + TAIL_OFF + 4096 + cl * 16) = z;    // tail chunk 1
    }
}

// ---------------------------------------------------------------------------
// main: classes-as-M GEMM, acc[class][batch] = dot(c,x) - cn/2  (s = -2*acc)
//  block 256 cls x 256 batch, 8 waves (2M x 4N), wave 128x64 (4x2 frags 32x32)
//  grid mapping: bid = cblk*64 + bblk  -> all 4 cblks of a bblk on one XCD
//  BK=32, 16 slabs, triple-buffered, depth-2 prefetch, counted vmcnt(6)
//  FULLY UNROLLED pipeline: all buffer indices / A-B register alternation are
//  compile-time constants; B staging regs are named struct members (no arrays,
//  no runtime pointer selects -> no localMem, rule #20).
//  LDS: A 3x16K @0 | B 3x16K @48K | tailA 8K @96K | scratch @104K
// ---------------------------------------------------------------------------
struct B4 { float4 a, b, c, d; };

__global__ __launch_bounds__(512, 2) void trip_main(
    const float* __restrict__ x, const int* __restrict__ labels,
    const char* __restrict__ cbt, float* __restrict__ mxp,
    float* __restrict__ dap)
{
    extern __shared__ char lds[];
    const int t    = threadIdx.x;
    const int lane = t & 63;
    const int w    = t >> 6;          // 0..7
    const int wN   = w & 3, wM = w >> 2;
    const int l31  = lane & 31, hi = lane >> 5;
    const int bid  = blockIdx.x;
    const int cblk = bid >> 6;        // 0..3
    const int bblk = bid & 63;        // 0..63 -> XCD = bblk & 7
    const int class0 = cblk * 256;
    const int row0   = bblk * 256;
    const char* cbB  = cbt + (size_t)cblk * CBLK_STRIDE;

    auto stageA = [&](int ko, int ai) {   // 16KB contiguous memcpy, 2 instr
        const char* src = cbB + ko * 16384 + w * 1024 + lane * 16;
        char* dst = lds + ai * 16384 + w * 1024 + lane * 16;
        __builtin_amdgcn_global_load_lds((const GLOBAL_AS void*)src,
                                         (LDS_AS void*)dst, 16, 0, 0);
        __builtin_amdgcn_global_load_lds((const GLOBAL_AS void*)(src + 8192),
                                         (LDS_AS void*)(dst + 8192), 16, 0, 0);
    };
    auto loadB = [&](int ko, B4& br) {    // 4 dwordx4, 8 full lines each
        const float* src = x + (size_t)row0 * FDIM + ko * 32
                         + (size_t)(w * 32 + (lane >> 3)) * FDIM + (lane & 7) * 4;
        br.a = *(const float4*)(src);
        br.b = *(const float4*)(src +  8 * FDIM);
        br.c = *(const float4*)(src + 16 * FDIM);
        br.d = *(const float4*)(src + 24 * FDIM);
    };
    auto cv4 = [](float4 f) {
        bf16x4 v;
        v[0] = (__bf16)f.x; v[1] = (__bf16)f.y;
        v[2] = (__bf16)f.z; v[3] = (__bf16)f.w;
        return v;
    };
    auto writeB = [&](const B4& br, int bi) {   // 4 ds_write_b64
        char* dst = lds + 49152 + bi * 16384 + ((lane & 7) >> 1) * 4096
                  + (w * 32 + (lane >> 3)) * 16 + (lane & 1) * 8;
        *(bf16x4*)(dst          ) = cv4(br.a);
        *(bf16x4*)(dst + 128    ) = cv4(br.b);
        *(bf16x4*)(dst + 256    ) = cv4(br.c);
        *(bf16x4*)(dst + 384    ) = cv4(br.d);
    };

    f32x16 acc[4][2];
    #pragma unroll
    for (int mi = 0; mi < 4; ++mi)
        #pragma unroll
        for (int ni = 0; ni < 2; ++ni)
            #pragma unroll
            for (int r = 0; r < 16; ++r) acc[mi][ni][r] = 0.f;

    auto compute = [&](int buf) {
        const char* A = lds + buf * 16384;
        const char* B = lds + 49152 + buf * 16384;
        #pragma unroll
        for (int ks = 0; ks < 2; ++ks) {
            const int chunk = ks * 2 + hi;
            bf16x8 a[4], b[2];
            #pragma unroll
            for (int mi = 0; mi < 4; ++mi)
                a[mi] = *(const bf16x8*)(A + chunk * 4096 + (wM * 128 + mi * 32 + l31) * 16);
            #pragma unroll
            for (int ni = 0; ni < 2; ++ni)
                b[ni] = *(const bf16x8*)(B + chunk * 4096 + (wN * 64 + ni * 32 + l31) * 16);
            #pragma unroll
            for (int mi = 0; mi < 4; ++mi)
                #pragma unroll
                for (int ni = 0; ni < 2; ++ni)
                    acc[mi][ni] = __builtin_amdgcn_mfma_f32_32x32x16_bf16(
                        a[mi], b[ni], acc[mi][ni], 0, 0, 0);
        }
    };

    // ---- prologue (vmem ledger: lab 2, tail 1, A0 2, B0 4 | A1 2, B1 4) ----
    const int lab0 = labels[row0 + wN * 64 + l31];
    const int lab1 = labels[row0 + wN * 64 + 32 + l31];
    {   // tail A: 8KB contiguous memcpy
        const char* src = cbB + TAIL_OFF + t * 16;
        char* dst = lds + 98304 + t * 16;
        __builtin_amdgcn_global_load_lds((const GLOBAL_AS void*)src,
                                         (LDS_AS void*)dst, 16, 0, 0);
    }
    B4 brA, brB;
    stageA(0, 0); loadB(0, brA);
    __builtin_amdgcn_sched_barrier(0);   // pin: {lab,tail,A0,B0} before {A1,B1}
    stageA(1, 1); loadB(1, brB);
    VMCNT(6);            // drain lab+tail+slab0; keep slab1's 6 in flight
    writeB(brA, 0);
    BAR();

    // ---- K pipeline: 16 slabs of 32, FULLY UNROLLED ----
    #pragma unroll
    for (int tt = 0; tt < 16; ++tt) {
        const int cur = tt % 3, wr = (tt + 1) % 3, pre = (tt + 2) % 3;
        if (tt < 14) {
            stageA(tt + 2, pre);
            if (tt & 1) loadB(tt + 2, brB);
            else        loadB(tt + 2, brA);
            VMCNT(6);    // drain slab tt+1 (A DMA + B regs); keep tt+2's 6
        } else {
            VMCNT(0);
        }
        if (tt < 15) {
            if (tt & 1) writeB(brA, wr);
            else        writeB(brB, wr);
        }
        compute(cur);
        BAR();
    }

    // ---- tail k-step (k 512..527): A from tail LDS, B = (1,1,0,...) ----
    {
        const char* T = lds + 98304;
        bf16x8 bt;
        #pragma unroll
        for (int e = 0; e < 8; ++e) bt[e] = (__bf16)0.f;
        if (hi == 0) { bt[0] = (__bf16)1.0f; bt[1] = (__bf16)1.0f; }
        #pragma unroll
        for (int mi = 0; mi < 4; ++mi) {
            bf16x8 a = *(const bf16x8*)(T + hi * 4096 + (wM * 128 + mi * 32 + l31) * 16);
            #pragma unroll
            for (int ni = 0; ni < 2; ++ni)
                acc[mi][ni] = __builtin_amdgcn_mfma_f32_32x32x16_bf16(
                    a, bt, acc[mi][ni], 0, 0, 0);
        }
    }

    // ---- epilogue: per-lane max over non-label classes + label acc ----
    const int labBase = class0 + wM * 128 + hi * 4;
    const int labA0 = lab0 - labBase;
    const int labA1 = lab1 - labBase;
    float MX0 = -3e38f, MX1 = -3e38f, DA0 = -3e38f, DA1 = -3e38f;
    #pragma unroll
    for (int mi = 0; mi < 4; ++mi) {
        #pragma unroll
        for (int r = 0; r < 16; ++r) {
            const int pat = mi * 32 + (r & 3) + 8 * (r >> 2);
            {
                const float a = acc[mi][0][r];
                const bool is = (labA0 == pat);
                MX0 = fmaxf(MX0, is ? -3e38f : a);
                DA0 = is ? a : DA0;
            }
            {
                const float a = acc[mi][1][r];
                const bool is = (labA1 == pat);
                MX1 = fmaxf(MX1, is ? -3e38f : a);
                DA1 = is ? a : DA1;
            }
        }
    }
    MX0 = fmaxf(MX0, __shfl_xor(MX0, 32));
    DA0 = fmaxf(DA0, __shfl_xor(DA0, 32));
    MX1 = fmaxf(MX1, __shfl_xor(MX1, 32));
    DA1 = fmaxf(DA1, __shfl_xor(DA1, 32));

    // ---- merge the two M-waves via scratch, store partials ----
    float* sc = (float*)(lds + 104 * 1024);   // [256] MX, [256] DA
    const int i0 = (wN * 2 + 0) * 32 + l31;
    const int i1 = (wN * 2 + 1) * 32 + l31;
    if (wM == 1 && hi == 0) {
        sc[i0] = MX0; sc[256 + i0] = DA0;
        sc[i1] = MX1; sc[256 + i1] = DA1;
    }
    __syncthreads();
    if (wM == 0 && hi == 0) {
        const float M0 = fmaxf(MX0, sc[i0]),  D0 = fmaxf(DA0, sc[256 + i0]);
        const float M1 = fmaxf(MX1, sc[i1]),  D1 = fmaxf(DA1, sc[256 + i1]);
        const int rg = row0 + wN * 64 + l31;
        mxp[cblk * BATCH + rg]      = M0;
        dap[cblk * BATCH + rg]      = D0;
        mxp[cblk * BATCH + rg + 32] = M1;
        dap[cblk * BATCH + rg + 32] = D1;
    }
}

// ---------------------------------------------------------------------------
__global__ __launch_bounds__(256) void combine1(
    const float* __restrict__ mxp, const float* __restrict__ dap,
    const float* __restrict__ margin, float* __restrict__ partial)
{
    const int t = threadIdx.x;
    const int row = blockIdx.x * 256 + t;
    float mx = mxp[row];
    mx = fmaxf(mx, mxp[BATCH + row]);
    mx = fmaxf(mx, mxp[2 * BATCH + row]);
    mx = fmaxf(mx, mxp[3 * BATCH + row]);
    float da = dap[row];
    da = fmaxf(da, dap[BATCH + row]);
    da = fmaxf(da, dap[2 * BATCH + row]);
    da = fmaxf(da, dap[3 * BATCH + row]);
    // dist = -2*da, dist_min = -2*mx
    float loss = fmaxf(margin[0] - 2.f * da + 2.f * mx, 0.f);
    __shared__ float red[4];
    #pragma unroll
    for (int o = 32; o > 0; o >>= 1) loss += __shfl_down(loss, o);
    if ((t & 63) == 0) red[t >> 6] = loss;
    __syncthreads();
    if (t == 0) partial[blockIdx.x] = red[0] + red[1] + red[2] + red[3];
}

__global__ __launch_bounds__(64) void combine2(
    const float* __restrict__ partial, float* __restrict__ out)
{
    float s = partial[threadIdx.x];
    #pragma unroll
    for (int o = 32; o > 0; o >>= 1) s += __shfl_down(s, o);
    if (threadIdx.x == 0) out[0] = s * (1.0f / BATCH);
}

// ---------------------------------------------------------------------------
extern "C" void kernel_launch(void* const* d_in, const int* in_sizes, int n_in,
                              void* d_out, int out_size, void* d_ws, size_t ws_size,
                              hipStream_t stream)
{
    const float* x       = (const float*)d_in[0];
    const int*   labels  = (const int*)d_in[1];
    const float* centers = (const float*)d_in[2];
    const float* margin  = (const float*)d_in[3];
    float* out = (float*)d_out;

    char* ws = (char*)d_ws;
    char*  cbt  = ws;                                  // 1,081,344 B
    float* mxp  = (float*)(ws + 1081344);              //   262,144 B
    float* dap  = (float*)(ws + 1343488);              //   262,144 B
    float* part = (float*)(ws + 1605632);              //       256 B

    (void)hipFuncSetAttribute((const void*)trip_main,
                              hipFuncAttributeMaxDynamicSharedMemorySize, 110592);

    prep_centers<<<NPAD, 64, 0, stream>>>(centers, cbt);
    trip_main<<<256, 512, 110592, stream>>>(x, labels, cbt, mxp, dap);
    combine1<<<64, 256, 0, stream>>>(mxp, dap, margin, part);
    combine2<<<1, 64, 0, stream>>>(part, out);
}

// Round 5
// 33.456 us; speedup vs baseline: 2.4828x; 1.0015x over previous
//
#include <hip/hip_runtime.h>
#include <hip/hip_bf16.h>

#define BATCH 16384
#define NCLS  1000
#define NPAD  1024
#define FDIM  512

// cbt layout per cblk: 16 slabs * 16KB ([chunk4][class256]x16B) + tail 4KB
#define CBLK_STRIDE 266240
#define TAIL_OFF    262144

typedef __bf16 bf16x4 __attribute__((ext_vector_type(4)));
typedef __bf16 bf16x8 __attribute__((ext_vector_type(8)));
typedef float  f32x16 __attribute__((ext_vector_type(16)));

#define GLOBAL_AS __attribute__((address_space(1)))
#define LDS_AS    __attribute__((address_space(3)))

#define VMCNT(n) asm volatile("s_waitcnt vmcnt(" #n ")" ::: "memory")
#define LGKM0()  asm volatile("s_waitcnt lgkmcnt(0)" ::: "memory")
#define BAR()    do { LGKM0(); __builtin_amdgcn_s_barrier(); \
                      __builtin_amdgcn_sched_barrier(0); } while (0)

// ---------------------------------------------------------------------------
// prep: centers fp32 [1000][512] -> cbt, pre-tiled to the main kernel's LDS
// slab image. k<512: bf16(center); tail chunk holds (h=bf16(-cn/2),
// l=residual, 0...); pad classes: zeros, h=-1e30.
// ---------------------------------------------------------------------------
__global__ __launch_bounds__(64) void prep_centers(
    const float* __restrict__ centers, char* __restrict__ cbt)
{
    const int c = blockIdx.x, t = threadIdx.x;       // c 0..1023, t 0..63
    const int cblk = c >> 8, cl = c & 255;
    char* base = cbt + (size_t)cblk * CBLK_STRIDE;

    float4 f0 = make_float4(0.f, 0.f, 0.f, 0.f);
    float4 f1 = make_float4(0.f, 0.f, 0.f, 0.f);
    if (c < NCLS) {
        f0 = *(const float4*)(centers + (size_t)c * FDIM + t * 8);
        f1 = *(const float4*)(centers + (size_t)c * FDIM + t * 8 + 4);
    }
    bf16x8 b;
    b[0] = (__bf16)f0.x; b[1] = (__bf16)f0.y; b[2] = (__bf16)f0.z; b[3] = (__bf16)f0.w;
    b[4] = (__bf16)f1.x; b[5] = (__bf16)f1.y; b[6] = (__bf16)f1.z; b[7] = (__bf16)f1.w;
    *(bf16x8*)(base + (t >> 2) * 16384 + (t & 3) * 4096 + cl * 16) = b;

    float ssum = f0.x*f0.x + f0.y*f0.y + f0.z*f0.z + f0.w*f0.w
               + f1.x*f1.x + f1.y*f1.y + f1.z*f1.z + f1.w*f1.w;
    #pragma unroll
    for (int o = 32; o > 0; o >>= 1) ssum += __shfl_down(ssum, o);
    if (t == 0) {
        const float hf = (c < NCLS) ? (-0.5f * ssum) : -1e30f;
        const __bf16 h = (__bf16)hf;
        const __bf16 l = (c < NCLS) ? (__bf16)(hf - (float)h) : (__bf16)0.f;
        bf16x8 tl;
        #pragma unroll
        for (int e = 0; e < 8; ++e) tl[e] = (__bf16)0.f;
        tl[0] = h; tl[1] = l;
        *(bf16x8*)(base + TAIL_OFF + cl * 16) = tl;
    }
}

// ---------------------------------------------------------------------------
// main: classes-as-M GEMM, acc[class][batch] = dot(c,x) - cn/2  (s = -2*acc)
//  block 256 cls x 128 batch, 4 waves (2M x 2N), wave 128x64 (4x2 frags 32x32)
//  grid = 4 cblk * 128 bblk = 512 blocks -> 2 blocks/CU (LDS 76K each):
//  two independent barrier domains per CU cover each other's drains.
//  BK=32, 16 slabs, triple-buffered, depth-2 prefetch, counted vmcnt(8)
//  A: cbt slab image -> contiguous memcpy via global_load_lds (4 instr/thread)
//  B: x fp32 reg-staged (4 coalesced dwordx4), cvt bf16, 4x ds_write_b64
//  LDS: A 3x16K @0 | B 3x8K @48K | tailA 4K @72K | sc reuses A buf0
// ---------------------------------------------------------------------------
struct B4 { float4 a, b, c, d; };

__global__ __launch_bounds__(256, 2) void trip_main(
    const float* __restrict__ x, const int* __restrict__ labels,
    const char* __restrict__ cbt, float* __restrict__ mxp,
    float* __restrict__ dap)
{
    extern __shared__ char lds[];
    const int t    = threadIdx.x;
    const int lane = t & 63;
    const int w    = t >> 6;          // 0..3
    const int wN   = w & 1, wM = w >> 1;
    const int l31  = lane & 31, hi = lane >> 5;
    const int bid  = blockIdx.x;
    const int cblk = bid >> 7;        // 0..3
    const int bblk = bid & 127;       // 0..127 -> XCD = bblk & 7
    const int class0 = cblk * 256;
    const int row0   = bblk * 128;
    const char* cbB  = cbt + (size_t)cblk * CBLK_STRIDE;

    auto stageA = [&](int ko, int ai) {   // 16KB contiguous memcpy, 4 instr
        const char* src = cbB + ko * 16384 + w * 4096 + lane * 16;
        char* dst = lds + ai * 16384 + w * 4096 + lane * 16;
        #pragma unroll
        for (int j = 0; j < 4; ++j)
            __builtin_amdgcn_global_load_lds(
                (const GLOBAL_AS void*)(src + j * 1024),
                (LDS_AS void*)(dst + j * 1024), 16, 0, 0);
    };
    auto loadB = [&](int ko, B4& br) {    // 4 dwordx4, 8 full lines each
        const float* src = x + (size_t)row0 * FDIM + ko * 32
                         + (size_t)(w * 32 + (lane >> 3)) * FDIM + (lane & 7) * 4;
        br.a = *(const float4*)(src);
        br.b = *(const float4*)(src +  8 * FDIM);
        br.c = *(const float4*)(src + 16 * FDIM);
        br.d = *(const float4*)(src + 24 * FDIM);
    };
    auto cv4 = [](float4 f) {
        bf16x4 v;
        v[0] = (__bf16)f.x; v[1] = (__bf16)f.y;
        v[2] = (__bf16)f.z; v[3] = (__bf16)f.w;
        return v;
    };
    auto writeB = [&](const B4& br, int bi) {   // 4 ds_write_b64
        char* dst = lds + 49152 + bi * 8192 + ((lane & 7) >> 1) * 2048
                  + (w * 32 + (lane >> 3)) * 16 + (lane & 1) * 8;
        *(bf16x4*)(dst      ) = cv4(br.a);
        *(bf16x4*)(dst + 128) = cv4(br.b);
        *(bf16x4*)(dst + 256) = cv4(br.c);
        *(bf16x4*)(dst + 384) = cv4(br.d);
    };

    f32x16 acc[4][2];
    #pragma unroll
    for (int mi = 0; mi < 4; ++mi)
        #pragma unroll
        for (int ni = 0; ni < 2; ++ni)
            #pragma unroll
            for (int r = 0; r < 16; ++r) acc[mi][ni][r] = 0.f;

    auto compute = [&](int buf) {
        const char* A = lds + buf * 16384;
        const char* B = lds + 49152 + buf * 8192;
        #pragma unroll
        for (int ks = 0; ks < 2; ++ks) {
            const int chunk = ks * 2 + hi;
            bf16x8 a[4], b[2];
            #pragma unroll
            for (int mi = 0; mi < 4; ++mi)
                a[mi] = *(const bf16x8*)(A + chunk * 4096 + (wM * 128 + mi * 32 + l31) * 16);
            #pragma unroll
            for (int ni = 0; ni < 2; ++ni)
                b[ni] = *(const bf16x8*)(B + chunk * 2048 + (wN * 64 + ni * 32 + l31) * 16);
            #pragma unroll
            for (int mi = 0; mi < 4; ++mi)
                #pragma unroll
                for (int ni = 0; ni < 2; ++ni)
                    acc[mi][ni] = __builtin_amdgcn_mfma_f32_32x32x16_bf16(
                        a[mi], b[ni], acc[mi][ni], 0, 0, 0);
        }
    };

    // ---- prologue (ledger: lab 2, tail 1, A0 4, B0 4 | A1 4, B1 4) ----
    const int lab0 = labels[row0 + wN * 64 + l31];
    const int lab1 = labels[row0 + wN * 64 + 32 + l31];
    {   // tail A: 4KB contiguous memcpy (1 instr/thread)
        const char* src = cbB + TAIL_OFF + t * 16;
        char* dst = lds + 73728 + t * 16;
        __builtin_amdgcn_global_load_lds((const GLOBAL_AS void*)src,
                                         (LDS_AS void*)dst, 16, 0, 0);
    }
    B4 brA, brB;
    stageA(0, 0); loadB(0, brA);
    __builtin_amdgcn_sched_barrier(0);   // pin: {lab,tail,A0,B0} before {A1,B1}
    stageA(1, 1); loadB(1, brB);
    VMCNT(8);            // drain lab+tail+slab0; keep slab1's 8 in flight
    writeB(brA, 0);
    BAR();

    // ---- K pipeline: 16 slabs of 32, FULLY UNROLLED ----
    #pragma unroll
    for (int tt = 0; tt < 16; ++tt) {
        const int cur = tt % 3, wr = (tt + 1) % 3, pre = (tt + 2) % 3;
        if (tt < 14) {
            stageA(tt + 2, pre);
            if (tt & 1) loadB(tt + 2, brB);
            else        loadB(tt + 2, brA);
            VMCNT(8);    // drain slab tt+1 (A DMA + B regs); keep tt+2's 8
        } else {
            VMCNT(0);
        }
        if (tt < 15) {
            if (tt & 1) writeB(brA, wr);
            else        writeB(brB, wr);
        }
        compute(cur);
        BAR();
    }

    // ---- tail k-step (k 512..527): A from tail LDS, B = (1,1,0,...) ----
    // hi=1 lanes have an all-zero B fragment, so their A value is don't-care:
    // read the same 4K tail chunk for both halves.
    {
        const char* T = lds + 73728;
        bf16x8 bt;
        #pragma unroll
        for (int e = 0; e < 8; ++e) bt[e] = (__bf16)0.f;
        if (hi == 0) { bt[0] = (__bf16)1.0f; bt[1] = (__bf16)1.0f; }
        #pragma unroll
        for (int mi = 0; mi < 4; ++mi) {
            bf16x8 a = *(const bf16x8*)(T + (wM * 128 + mi * 32 + l31) * 16);
            #pragma unroll
            for (int ni = 0; ni < 2; ++ni)
                acc[mi][ni] = __builtin_amdgcn_mfma_f32_32x32x16_bf16(
                    a, bt, acc[mi][ni], 0, 0, 0);
        }
    }

    // ---- epilogue: per-lane max over non-label classes + label acc ----
    const int labBase = class0 + wM * 128 + hi * 4;
    const int labA0 = lab0 - labBase;
    const int labA1 = lab1 - labBase;
    float MX0 = -3e38f, MX1 = -3e38f, DA0 = -3e38f, DA1 = -3e38f;
    #pragma unroll
    for (int mi = 0; mi < 4; ++mi) {
        #pragma unroll
        for (int r = 0; r < 16; ++r) {
            const int pat = mi * 32 + (r & 3) + 8 * (r >> 2);
            {
                const float a = acc[mi][0][r];
                const bool is = (labA0 == pat);
                MX0 = fmaxf(MX0, is ? -3e38f : a);
                DA0 = is ? a : DA0;
            }
            {
                const float a = acc[mi][1][r];
                const bool is = (labA1 == pat);
                MX1 = fmaxf(MX1, is ? -3e38f : a);
                DA1 = is ? a : DA1;
            }
        }
    }
    MX0 = fmaxf(MX0, __shfl_xor(MX0, 32));
    DA0 = fmaxf(DA0, __shfl_xor(DA0, 32));
    MX1 = fmaxf(MX1, __shfl_xor(MX1, 32));
    DA1 = fmaxf(DA1, __shfl_xor(DA1, 32));

    // ---- merge the two M-waves via scratch (reuse A buf0), store ----
    float* sc = (float*)lds;              // [128] MX, [128] DA
    const int i0 = wN * 64 + l31;
    const int i1 = i0 + 32;
    if (wM == 1 && hi == 0) {
        sc[i0] = MX0; sc[128 + i0] = DA0;
        sc[i1] = MX1; sc[128 + i1] = DA1;
    }
    __syncthreads();
    if (wM == 0 && hi == 0) {
        const float M0 = fmaxf(MX0, sc[i0]),  D0 = fmaxf(DA0, sc[128 + i0]);
        const float M1 = fmaxf(MX1, sc[i1]),  D1 = fmaxf(DA1, sc[128 + i1]);
        const int rg = row0 + wN * 64 + l31;
        mxp[cblk * BATCH + rg]      = M0;
        dap[cblk * BATCH + rg]      = D0;
        mxp[cblk * BATCH + rg + 32] = M1;
        dap[cblk * BATCH + rg + 32] = D1;
    }
}

// ---------------------------------------------------------------------------
__global__ __launch_bounds__(256) void combine1(
    const float* __restrict__ mxp, const float* __restrict__ dap,
    const float* __restrict__ margin, float* __restrict__ partial)
{
    const int t = threadIdx.x;
    const int row = blockIdx.x * 256 + t;
    float mx = mxp[row];
    mx = fmaxf(mx, mxp[BATCH + row]);
    mx = fmaxf(mx, mxp[2 * BATCH + row]);
    mx = fmaxf(mx, mxp[3 * BATCH + row]);
    float da = dap[row];
    da = fmaxf(da, dap[BATCH + row]);
    da = fmaxf(da, dap[2 * BATCH + row]);
    da = fmaxf(da, dap[3 * BATCH + row]);
    // dist = -2*da, dist_min = -2*mx
    float loss = fmaxf(margin[0] - 2.f * da + 2.f * mx, 0.f);
    __shared__ float red[4];
    #pragma unroll
    for (int o = 32; o > 0; o >>= 1) loss += __shfl_down(loss, o);
    if ((t & 63) == 0) red[t >> 6] = loss;
    __syncthreads();
    if (t == 0) partial[blockIdx.x] = red[0] + red[1] + red[2] + red[3];
}

__global__ __launch_bounds__(64) void combine2(
    const float* __restrict__ partial, float* __restrict__ out)
{
    float s = partial[threadIdx.x];
    #pragma unroll
    for (int o = 32; o > 0; o >>= 1) s += __shfl_down(s, o);
    if (threadIdx.x == 0) out[0] = s * (1.0f / BATCH);
}

// ---------------------------------------------------------------------------
extern "C" void kernel_launch(void* const* d_in, const int* in_sizes, int n_in,
                              void* d_out, int out_size, void* d_ws, size_t ws_size,
                              hipStream_t stream)
{
    const float* x       = (const float*)d_in[0];
    const int*   labels  = (const int*)d_in[1];
    const float* centers = (const float*)d_in[2];
    const float* margin  = (const float*)d_in[3];
    float* out = (float*)d_out;

    char* ws = (char*)d_ws;
    char*  cbt  = ws;                                  // 1,064,960 B
    float* mxp  = (float*)(ws + 1064960);              //   262,144 B
    float* dap  = (float*)(ws + 1327104);              //   262,144 B
    float* part = (float*)(ws + 1589248);              //       256 B

    (void)hipFuncSetAttribute((const void*)trip_main,
                              hipFuncAttributeMaxDynamicSharedMemorySize, 77824);

    prep_centers<<<NPAD, 64, 0, stream>>>(centers, cbt);
    trip_main<<<512, 256, 77824, stream>>>(x, labels, cbt, mxp, dap);
    combine1<<<64, 256, 0, stream>>>(mxp, dap, margin, part);
    combine2<<<1, 64, 0, stream>>>(part, out);
}